// Round 1
// 334.707 us; speedup vs baseline: 1.1581x; 1.1581x over previous
//
#include <hip/hip_runtime.h>
#include <math.h>

// ---------------------------------------------------------------------------
// K1 (v2): fused maxpool3x3(stride1,pad1) + blurpool(4x4 [1,3,3,1]^2/64,
//          stride3, reflect pad (1,2)) : x (plane,192,192) -> xtem (plane,64,64)
//
// Per-output formulation: out[i][j] depends only on the 6x6 input patch at
// rows 3i-2..3i+3, cols 3j-2..3j+3. One block = 1 plane x 4 output rows:
// stage 15 input rows (row-clamped: edge replication == max-window clamping),
// ONE barrier, then each thread computes its pixel entirely in registers:
//   vmu[u][k] = 3-row max (window u..u+2 of the thread's 6 staged rows)
//   h[v]      = 3-col max of vmu[u] (window v..v+2 of the 6 clamped cols)
//   cbv[u]    = [1,3,3,1] col blur;  acc = [1,3,3,1] row blur / 64
// Reflect edges: i=0,u=0 tap == window of u=2; j=0,v=0 tap == window of v=2
// (1-op selects). No phase serialization, no idle lanes, ~2-way LDS aliasing
// (free). LDS 11.5 KB -> 8 blocks/CU.
// ---------------------------------------------------------------------------
__global__ __launch_bounds__(256) void k1_pool(const float* __restrict__ x,
                                               float* __restrict__ xtem) {
    const int plane = blockIdx.y;            // 0..1023
    const int i0 = blockIdx.x * 4;           // 4 output rows per block
    const int base = 3 * i0 - 2;             // first staged input row (unclamped)

    __shared__ float xs[15 * 192];           // 11.5 KB

    const float* xp = x + (size_t)plane * (192 * 192);
    // stage 15 rows (row-clamped at plane edges), float4 coalesced
    for (int f = threadIdx.x; f < 15 * 48; f += 256) {
        int r = f / 48, c4 = f - r * 48;
        int src = min(max(base + r, 0), 191);
        ((float4*)xs)[f] = ((const float4*)(xp + (size_t)src * 192))[c4];
    }
    __syncthreads();

    const int j = threadIdx.x & 63;          // output column
    const int il = threadIdx.x >> 6;         // 0..3, local output row
    const int i = i0 + il;

    // clamped global cols 3j-2 .. 3j+3  (clamp == replicate, valid for max)
    int colk[6];
#pragma unroll
    for (int k = 0; k < 6; ++k)
        colk[k] = min(max(3 * j - 2 + k, 0), 191);

    // vertical 3-max: vmu[u][k] = max over staged rows (3*il+u .. 3*il+u+2)
    float vmu[4][6];
#pragma unroll
    for (int k = 0; k < 6; ++k) {
        const float* cp = xs + 3 * il * 192 + colk[k];
        float p0 = cp[0 * 192], p1 = cp[1 * 192], p2 = cp[2 * 192];
        float p3 = cp[3 * 192], p4 = cp[4 * 192], p5 = cp[5 * 192];
        float q1 = fmaxf(p1, p2), q2 = fmaxf(p2, p3);
        float q3 = fmaxf(p3, p4), q4 = fmaxf(p4, p5);
        vmu[0][k] = fmaxf(p0, q1);
        vmu[1][k] = fmaxf(p1, q2);
        vmu[2][k] = fmaxf(p2, q3);
        vmu[3][k] = fmaxf(p3, q4);
    }

    // horizontal 3-max + column blur [1,3,3,1]
    float cbv[4];
#pragma unroll
    for (int u = 0; u < 4; ++u) {
        float g1 = fmaxf(vmu[u][1], vmu[u][2]);
        float g2 = fmaxf(vmu[u][2], vmu[u][3]);
        float g3 = fmaxf(vmu[u][3], vmu[u][4]);
        float g4 = fmaxf(vmu[u][4], vmu[u][5]);
        float h0 = fmaxf(vmu[u][0], g1);     // cols k0..k2
        float h1 = fmaxf(vmu[u][1], g2);     // cols k1..k3
        float h2 = fmaxf(vmu[u][2], g3);     // cols k2..k4
        float h3 = fmaxf(vmu[u][3], g4);     // cols k3..k5
        float ha = (j == 0) ? h2 : h0;       // col reflect: c=-1 -> window of v=2
        cbv[u] = ha + 3.f * h1 + 3.f * h2 + h3;
    }
    // row blur [1,3,3,1] with reflect: m=-1 -> window of u=2
    float c0 = (i == 0) ? cbv[2] : cbv[0];
    float acc = c0 + 3.f * cbv[1] + 3.f * cbv[2] + cbv[3];
    xtem[(size_t)plane * 4096 + i * 64 + j] = acc * (1.f / 64.f);
}

// ---------------------------------------------------------------------------
// K2: att = h1 + w1 + h2(diag) + w2(diag) on x_tem, then BN + sigmoid -> gate.
// Direct stencils (zero-padded, bounded by the 64x64 tile):
//   h1[i,j] = sum_{p<11,q<3} Wh1[p][q] T[i+p-5][j+q-1]
//   h2[i,j] = sum_{p<11,q<3} Wh2[p][q] T[i+p-5][j+q+4-p]
//   w1[i,j] = sum_{p<3,q<11} Wv1[p][q] T[i+p-1][j+q-5]
//   w2[i,j] = sum_{p<3,q<11} Wv2[p][q] T[i+p-q+4][j+q-5]
// TWO PASSES to keep live weights at 66 (no spills): pass H (Wh1,Wh2) buffers
// partial rows in LDS att[]; pass V (Wv1,Wv2) adds + BN + sigmoid.
// Rolling 13-deep accumulator: processing input row t, a tap with row offset
// dr = t - i lands in acc[6 - dr]; output i = t-6 reads acc[0], then shift.
// Block = 1 plane, 4 waves = 4 strips of 16 rows; lane = column j.
// ---------------------------------------------------------------------------
__global__ __launch_bounds__(256) void k2_att(
    const float* __restrict__ xtem,
    const float* __restrict__ wh1g, const float* __restrict__ wv1g,
    const float* __restrict__ wh2g, const float* __restrict__ wv2g,
    const float* __restrict__ gamma, const float* __restrict__ beta,
    const float* __restrict__ mean, const float* __restrict__ var,
    float* __restrict__ gate) {
    const int plane = blockIdx.x;          // 0..1023
    const int c = plane & 63;
    __shared__ float T[64 * 80];           // cols 6..69 live, rest zero
    __shared__ float att[64 * 64];

    for (int e = threadIdx.x; e < 64 * 80; e += 256) T[e] = 0.f;
    __syncthreads();
    for (int e = threadIdx.x; e < 4096; e += 256)
        T[(e >> 6) * 80 + 6 + (e & 63)] = xtem[(size_t)plane * 4096 + e];

    const float inv = gamma[c] * rsqrtf(var[c] + 1e-5f);
    const float bias = beta[c] - mean[c] * inv;
    __syncthreads();

    const int j = threadIdx.x & 63;
    const int ib = (threadIdx.x >> 6) * 16;   // strip base row

    float Wa[33], Wb[33];
    float acc[13];

    // ---- Pass H: h1 + h2 ----
#pragma unroll
    for (int k = 0; k < 33; ++k) {
        Wa[k] = wh1g[c * 33 + k];
        Wb[k] = wh2g[c * 33 + k];
    }
#pragma unroll
    for (int k = 0; k < 13; ++k) acc[k] = 0.f;
    for (int t = ib - 6; t <= ib + 21; ++t) {
        if (t >= 0 && t < 64) {
            float w_[13];
#pragma unroll
            for (int d = 0; d < 13; ++d) w_[d] = T[t * 80 + j + d];
#pragma unroll
            for (int p = 0; p < 11; ++p) {
                acc[11 - p] += Wa[p * 3 + 0] * w_[5] + Wa[p * 3 + 1] * w_[6] +
                               Wa[p * 3 + 2] * w_[7] +
                               Wb[p * 3 + 0] * w_[10 - p] +
                               Wb[p * 3 + 1] * w_[11 - p] +
                               Wb[p * 3 + 2] * w_[12 - p];
            }
        }
        int i = t - 6;
        if (i >= ib) att[i * 64 + j] = acc[0];
#pragma unroll
        for (int k = 0; k < 12; ++k) acc[k] = acc[k + 1];
        acc[12] = 0.f;
    }

    // ---- Pass V: w1 + w2, then BN + sigmoid ----
#pragma unroll
    for (int k = 0; k < 33; ++k) {
        Wa[k] = wv1g[c * 33 + k];
        Wb[k] = wv2g[c * 33 + k];
    }
#pragma unroll
    for (int k = 0; k < 13; ++k) acc[k] = 0.f;
    float* gp = gate + (size_t)plane * 4096;
    for (int t = ib - 6; t <= ib + 21; ++t) {
        if (t >= 0 && t < 64) {
            float w_[13];
#pragma unroll
            for (int d = 0; d < 13; ++d) w_[d] = T[t * 80 + j + d];
#pragma unroll
            for (int p = 0; p < 3; ++p) {
#pragma unroll
                for (int q = 0; q < 11; ++q) {
                    acc[7 - p] += Wa[p * 11 + q] * w_[q + 1];
                    acc[2 - p + q] += Wb[p * 11 + q] * w_[q + 1];
                }
            }
        }
        int i = t - 6;
        if (i >= ib) {
            float z = (att[i * 64 + j] + acc[0]) * inv + bias;
            gp[i * 64 + j] = 1.f / (1.f + __expf(-z));
        }
#pragma unroll
        for (int k = 0; k < 12; ++k) acc[k] = acc[k + 1];
        acc[12] = 0.f;
    }
}

// ---------------------------------------------------------------------------
// K3: out = x * gate[i/3, j/3], float4 streaming. 4 consecutive j span exactly
// 2 gate cells (g0, g0+1).
// ---------------------------------------------------------------------------
__global__ __launch_bounds__(256) void k3_mul(const float* __restrict__ x,
                                              const float* __restrict__ gate,
                                              float* __restrict__ out) {
    int idx = blockIdx.x * 256 + threadIdx.x;      // float4 index, < 9437184
    int j4 = idx % 48;
    int rest = idx / 48;
    int i = rest % 192;
    int plane = rest / 192;
    float4 xv = ((const float4*)x)[idx];
    const float* gp = gate + (size_t)plane * 4096 + (i / 3) * 64;
    int jj = 4 * j4;
    int g0 = jj / 3;
    int r = jj - 3 * g0;
    float ga = gp[g0], gb = gp[g0 + 1];
    float4 o;
    o.x = xv.x * ga;
    o.y = xv.y * (r == 2 ? gb : ga);
    o.z = xv.z * (r == 0 ? ga : gb);
    o.w = xv.w * gb;
    ((float4*)out)[idx] = o;
}

extern "C" void kernel_launch(void* const* d_in, const int* in_sizes, int n_in,
                              void* d_out, int out_size, void* d_ws, size_t ws_size,
                              hipStream_t stream) {
    const float* x     = (const float*)d_in[0];
    const float* wh1   = (const float*)d_in[1];
    const float* wv1   = (const float*)d_in[2];
    const float* wh2   = (const float*)d_in[3];
    const float* wv2   = (const float*)d_in[4];
    const float* gamma = (const float*)d_in[5];
    const float* beta  = (const float*)d_in[6];
    const float* mean  = (const float*)d_in[7];
    const float* var   = (const float*)d_in[8];
    float* out  = (float*)d_out;
    float* xtem = (float*)d_ws;                 // 1024*4096 floats = 16 MB
    float* gate = xtem + (size_t)1024 * 4096;   // 16 MB

    k1_pool<<<dim3(16, 1024), 256, 0, stream>>>(x, xtem);
    k2_att<<<1024, 256, 0, stream>>>(xtem, wh1, wv1, wh2, wv2,
                                     gamma, beta, mean, var, gate);
    k3_mul<<<36864, 256, 0, stream>>>(x, gate, out);
}

// Round 2
// 320.820 us; speedup vs baseline: 1.2082x; 1.0433x over previous
//
#include <hip/hip_runtime.h>
#include <math.h>

// ---------------------------------------------------------------------------
// K1: fused maxpool3x3(stride1,pad1) + blurpool(4x4 [1,3,3,1]^2/64,
//     stride3, reflect pad (1,2)) : x (plane,192,192) -> xtem (plane,64,64)
// Per-output formulation: out[i][j] depends only on the 6x6 input patch at
// rows 3i-2..3i+3, cols 3j-2..3j+3. One block = 1 plane x 4 output rows:
// stage 15 input rows (row-clamped: edge replication == max-window clamping),
// ONE barrier, then each thread computes its pixel entirely in registers.
// Reflect edges: i=0,u=0 tap == window of u=2; j=0,v=0 tap == window of v=2.
// ---------------------------------------------------------------------------
__global__ __launch_bounds__(256) void k1_pool(const float* __restrict__ x,
                                               float* __restrict__ xtem) {
    const int plane = blockIdx.y;            // 0..1023
    const int i0 = blockIdx.x * 4;           // 4 output rows per block
    const int base = 3 * i0 - 2;             // first staged input row (unclamped)

    __shared__ float xs[15 * 192];           // 11.5 KB

    const float* xp = x + (size_t)plane * (192 * 192);
    for (int f = threadIdx.x; f < 15 * 48; f += 256) {
        int r = f / 48, c4 = f - r * 48;
        int src = min(max(base + r, 0), 191);
        ((float4*)xs)[f] = ((const float4*)(xp + (size_t)src * 192))[c4];
    }
    __syncthreads();

    const int j = threadIdx.x & 63;          // output column
    const int il = threadIdx.x >> 6;         // 0..3, local output row
    const int i = i0 + il;

    int colk[6];
#pragma unroll
    for (int k = 0; k < 6; ++k)
        colk[k] = min(max(3 * j - 2 + k, 0), 191);

    float vmu[4][6];
#pragma unroll
    for (int k = 0; k < 6; ++k) {
        const float* cp = xs + 3 * il * 192 + colk[k];
        float p0 = cp[0 * 192], p1 = cp[1 * 192], p2 = cp[2 * 192];
        float p3 = cp[3 * 192], p4 = cp[4 * 192], p5 = cp[5 * 192];
        float q1 = fmaxf(p1, p2), q2 = fmaxf(p2, p3);
        float q3 = fmaxf(p3, p4), q4 = fmaxf(p4, p5);
        vmu[0][k] = fmaxf(p0, q1);
        vmu[1][k] = fmaxf(p1, q2);
        vmu[2][k] = fmaxf(p2, q3);
        vmu[3][k] = fmaxf(p3, q4);
    }

    float cbv[4];
#pragma unroll
    for (int u = 0; u < 4; ++u) {
        float g1 = fmaxf(vmu[u][1], vmu[u][2]);
        float g2 = fmaxf(vmu[u][2], vmu[u][3]);
        float g3 = fmaxf(vmu[u][3], vmu[u][4]);
        float g4 = fmaxf(vmu[u][4], vmu[u][5]);
        float h0 = fmaxf(vmu[u][0], g1);
        float h1 = fmaxf(vmu[u][1], g2);
        float h2 = fmaxf(vmu[u][2], g3);
        float h3 = fmaxf(vmu[u][3], g4);
        float ha = (j == 0) ? h2 : h0;       // col reflect
        cbv[u] = ha + 3.f * h1 + 3.f * h2 + h3;
    }
    float c0 = (i == 0) ? cbv[2] : cbv[0];   // row reflect
    float acc = c0 + 3.f * cbv[1] + 3.f * cbv[2] + cbv[3];
    xtem[(size_t)plane * 4096 + i * 64 + j] = acc * (1.f / 64.f);
}

// ---------------------------------------------------------------------------
// K2+K3 fused: att = h1 + w1 + h2(diag) + w2(diag), BN + sigmoid -> gate kept
// in LDS (att[] in place), then stream out = x * gate_up for the plane.
//
// Stencils (zero-padded within the 64x64 tile):
//   h1[i,j] = sum_{p<11,q<3} Wh1[p][q] T[i+p-5][j+q-1]
//   h2[i,j] = sum_{p<11,q<3} Wh2[p][q] T[i+p-5][j+q+4-p]
//   w1[i,j] = sum_{p<3,q<11} Wv1[p][q] T[i+p-1][j+q-5]
//   w2[i,j] = sum_{p<3,q<11} Wv2[p][q] T[i+p-q+4][j+q-5]
// TWO PASSES keep live weights at 66. Rolling 13-deep accumulator is now a
// ROTATING register file: processing input row t = t0+tt, a tap for output i
// lands at physical index (tt + (i-(t-6))) % 13; output i=t-6 is emitted from
// phys (tt % 13), which is then zeroed (it becomes next iter's k=12 slot).
// Full unroll (tt compile-time) => no shift movs, compile-time emit guard.
// Block = 1 plane, 4 waves = 4 strips of 16 rows; lane = column j.
// ---------------------------------------------------------------------------
__global__ __launch_bounds__(256) void k2_att_mul(
    const float* __restrict__ xtem, const float* __restrict__ x,
    const float* __restrict__ wh1g, const float* __restrict__ wv1g,
    const float* __restrict__ wh2g, const float* __restrict__ wv2g,
    const float* __restrict__ gamma, const float* __restrict__ beta,
    const float* __restrict__ mean, const float* __restrict__ var,
    float* __restrict__ out) {
    const int plane = blockIdx.x;          // 0..1023
    const int c = plane & 63;
    __shared__ float T[64 * 80];           // cols 6..69 live, rest zero
    __shared__ float att[64 * 64];         // partials -> gate (in place)

    for (int e = threadIdx.x; e < 64 * 80; e += 256) T[e] = 0.f;
    __syncthreads();
    for (int e = threadIdx.x; e < 4096; e += 256)
        T[(e >> 6) * 80 + 6 + (e & 63)] = xtem[(size_t)plane * 4096 + e];

    const float inv = gamma[c] * rsqrtf(var[c] + 1e-5f);
    const float bias = beta[c] - mean[c] * inv;
    __syncthreads();

    const int j = threadIdx.x & 63;
    const int ib = (threadIdx.x >> 6) * 16;   // strip base row
    const int t0 = ib - 6;

    float Wa[33], Wb[33];
    float racc[13];

    // ---- Pass H: h1 + h2 ----
#pragma unroll
    for (int k = 0; k < 33; ++k) {
        Wa[k] = wh1g[c * 33 + k];
        Wb[k] = wh2g[c * 33 + k];
    }
#pragma unroll
    for (int k = 0; k < 13; ++k) racc[k] = 0.f;
#pragma unroll
    for (int tt = 0; tt < 28; ++tt) {
        const int t = t0 + tt;
        if (t >= 0 && t < 64) {            // wave-uniform
            float w_[13];
#pragma unroll
            for (int d = 0; d < 13; ++d) w_[d] = T[t * 80 + j + d];
#pragma unroll
            for (int p = 0; p < 11; ++p) {
                racc[(tt + 11 - p) % 13] +=
                    Wa[p * 3 + 0] * w_[5] + Wa[p * 3 + 1] * w_[6] +
                    Wa[p * 3 + 2] * w_[7] +
                    Wb[p * 3 + 0] * w_[10 - p] +
                    Wb[p * 3 + 1] * w_[11 - p] +
                    Wb[p * 3 + 2] * w_[12 - p];
            }
        }
        if (tt >= 12) {                    // i = ib + tt - 12 >= ib
            const int i = t - 6;
            att[i * 64 + j] = racc[tt % 13];
        }
        racc[tt % 13] = 0.f;
    }

    // ---- Pass V: w1 + w2, then BN + sigmoid -> gate in att[] ----
#pragma unroll
    for (int k = 0; k < 33; ++k) {
        Wa[k] = wv1g[c * 33 + k];
        Wb[k] = wv2g[c * 33 + k];
    }
#pragma unroll
    for (int k = 0; k < 13; ++k) racc[k] = 0.f;
#pragma unroll
    for (int tt = 0; tt < 28; ++tt) {
        const int t = t0 + tt;
        if (t >= 0 && t < 64) {            // wave-uniform
            float w_[13];
#pragma unroll
            for (int d = 0; d < 13; ++d) w_[d] = T[t * 80 + j + d];
#pragma unroll
            for (int p = 0; p < 3; ++p) {
#pragma unroll
                for (int q = 0; q < 11; ++q) {
                    racc[(tt + 7 - p) % 13] += Wa[p * 11 + q] * w_[q + 1];
                    racc[(tt + 2 - p + q) % 13] += Wb[p * 11 + q] * w_[q + 1];
                }
            }
        }
        if (tt >= 12) {
            const int i = t - 6;
            float z = (att[i * 64 + j] + racc[tt % 13]) * inv + bias;
            att[i * 64 + j] = 1.f / (1.f + __expf(-z));   // gate, in place
        }
        racc[tt % 13] = 0.f;
    }
    __syncthreads();

    // ---- K3 tail: out = x * gate[i/3, j/3], float4, 4-deep MLP ----
    const float4* xp4 = (const float4*)(x + (size_t)plane * 36864);
    float4* op4 = (float4*)(out + (size_t)plane * 36864);
#pragma unroll
    for (int bse = 0; bse < 9216; bse += 1024) {
        float4 xv[4];
        int e[4];
#pragma unroll
        for (int u = 0; u < 4; ++u) {
            e[u] = bse + u * 256 + threadIdx.x;
            xv[u] = xp4[e[u]];
        }
#pragma unroll
        for (int u = 0; u < 4; ++u) {
            int i = e[u] / 48, c4 = e[u] - i * 48;
            const float* gp = att + (i / 3) * 64;
            int jj = 4 * c4;
            int g0 = jj / 3;
            int r = jj - 3 * g0;
            float ga = gp[g0], gb = gp[g0 + 1];
            float4 o;
            o.x = xv[u].x * ga;
            o.y = xv[u].y * (r == 2 ? gb : ga);
            o.z = xv[u].z * (r == 0 ? ga : gb);
            o.w = xv[u].w * gb;
            op4[e[u]] = o;
        }
    }
}

extern "C" void kernel_launch(void* const* d_in, const int* in_sizes, int n_in,
                              void* d_out, int out_size, void* d_ws, size_t ws_size,
                              hipStream_t stream) {
    const float* x     = (const float*)d_in[0];
    const float* wh1   = (const float*)d_in[1];
    const float* wv1   = (const float*)d_in[2];
    const float* wh2   = (const float*)d_in[3];
    const float* wv2   = (const float*)d_in[4];
    const float* gamma = (const float*)d_in[5];
    const float* beta  = (const float*)d_in[6];
    const float* mean  = (const float*)d_in[7];
    const float* var   = (const float*)d_in[8];
    float* out  = (float*)d_out;
    float* xtem = (float*)d_ws;                 // 1024*4096 floats = 16 MB

    k1_pool<<<dim3(16, 1024), 256, 0, stream>>>(x, xtem);
    k2_att_mul<<<1024, 256, 0, stream>>>(xtem, x, wh1, wv1, wh2, wv2,
                                         gamma, beta, mean, var, out);
}

// Round 3
// 311.930 us; speedup vs baseline: 1.2426x; 1.0285x over previous
//
#include <hip/hip_runtime.h>
#include <math.h>

// ---------------------------------------------------------------------------
// Fully fused MRA: one block = one plane (1024 blocks, 256 threads).
//
// Phase A (pooling): maxpool3x3(s1,p1) + blurpool([1,3,3,1]^2/64, s3,
//   reflect(1,2)) computed per-output from its 6x6 input patch. 16 chunks of
//   4 output rows; each chunk stages 15 input rows (row-clamped) into LDS
//   that ALIASES att[] (att not live yet), and writes pooled rows straight
//   into T[] (cols 6..69; borders stay zero = stencil zero-pad). No xtem in
//   HBM at all.
// Phase B (stencil): att = h1 + w1 + h2(diag) + w2(diag), BN + sigmoid.
//   h1[i,j] = sum_{p<11,q<3} Wh1[p][q] T[i+p-5][j+q-1]
//   h2[i,j] = sum_{p<11,q<3} Wh2[p][q] T[i+p-5][j+q+4-p]
//   w1[i,j] = sum_{p<3,q<11} Wv1[p][q] T[i+p-1][j+q-5]
//   w2[i,j] = sum_{p<3,q<11} Wv2[p][q] T[i+p-q+4][j+q-5]
//   Two passes (live weights 66, no spills). Rolling 13-deep accumulator as a
//   ROTATING register file: at input row t = t0+tt, tap for output i lands at
//   phys (tt + (i-(t-6))) % 13; output i=t-6 emits from phys (tt%13), then
//   that slot is zeroed. Full unroll => no shift movs. Gate kept in att[].
// Phase C (tail): out = x * gate[i/3, j/3], float4, 4-deep MLP. The plane's
//   x was read ~15 us earlier by phase A => L2/L3 hot.
//
// LDS = T(20480 B) + att(16384 B) = 36864 B -> 4 blocks/CU;
// __launch_bounds__(256,4) pins VGPR<=128 so waves, not registers, limit.
// ---------------------------------------------------------------------------
__global__ __launch_bounds__(256, 4) void mra_fused(
    const float* __restrict__ x,
    const float* __restrict__ wh1g, const float* __restrict__ wv1g,
    const float* __restrict__ wh2g, const float* __restrict__ wv2g,
    const float* __restrict__ gamma, const float* __restrict__ beta,
    const float* __restrict__ mean, const float* __restrict__ var,
    float* __restrict__ out) {
    const int plane = blockIdx.x;          // 0..1023
    const int c = plane & 63;
    __shared__ float T[64 * 80];           // pooled tile, cols 6..69 live
    __shared__ float att[64 * 64];         // pool-staging alias -> partials -> gate

    for (int e = threadIdx.x; e < 64 * 80; e += 256) T[e] = 0.f;
    __syncthreads();

    const int j = threadIdx.x & 63;        // column lane
    const int il = threadIdx.x >> 6;       // 0..3

    // ---- Phase A: pooling, 16 chunks of 4 output rows ----
    {
        float* xs = att;                   // 15*192 floats = 11.25 KB <= 16 KB
        const float* xp = x + (size_t)plane * 36864;

        int colk[6];
#pragma unroll
        for (int k = 0; k < 6; ++k)
            colk[k] = min(max(3 * j - 2 + k, 0), 191);

        for (int chunk = 0; chunk < 16; ++chunk) {
            const int i0 = chunk * 4;
            const int base = 3 * i0 - 2;   // first staged row (unclamped)
            for (int f = threadIdx.x; f < 15 * 48; f += 256) {
                int r = f / 48, c4 = f - r * 48;
                int src = min(max(base + r, 0), 191);
                ((float4*)xs)[f] = ((const float4*)(xp + (size_t)src * 192))[c4];
            }
            __syncthreads();

            const int i = i0 + il;
            float vmu[4][6];
#pragma unroll
            for (int k = 0; k < 6; ++k) {
                const float* cp = xs + 3 * il * 192 + colk[k];
                float p0 = cp[0 * 192], p1 = cp[1 * 192], p2 = cp[2 * 192];
                float p3 = cp[3 * 192], p4 = cp[4 * 192], p5 = cp[5 * 192];
                float q1 = fmaxf(p1, p2), q2 = fmaxf(p2, p3);
                float q3 = fmaxf(p3, p4), q4 = fmaxf(p4, p5);
                vmu[0][k] = fmaxf(p0, q1);
                vmu[1][k] = fmaxf(p1, q2);
                vmu[2][k] = fmaxf(p2, q3);
                vmu[3][k] = fmaxf(p3, q4);
            }
            float cbv[4];
#pragma unroll
            for (int u = 0; u < 4; ++u) {
                float g1 = fmaxf(vmu[u][1], vmu[u][2]);
                float g2 = fmaxf(vmu[u][2], vmu[u][3]);
                float g3 = fmaxf(vmu[u][3], vmu[u][4]);
                float g4 = fmaxf(vmu[u][4], vmu[u][5]);
                float h0 = fmaxf(vmu[u][0], g1);
                float h1 = fmaxf(vmu[u][1], g2);
                float h2 = fmaxf(vmu[u][2], g3);
                float h3 = fmaxf(vmu[u][3], g4);
                float ha = (j == 0) ? h2 : h0;         // col reflect
                cbv[u] = ha + 3.f * h1 + 3.f * h2 + h3;
            }
            float c0 = (i == 0) ? cbv[2] : cbv[0];     // row reflect
            float acc = c0 + 3.f * cbv[1] + 3.f * cbv[2] + cbv[3];
            T[i * 80 + 6 + j] = acc * (1.f / 64.f);
            __syncthreads();               // guard xs overwrite / T completion
        }
    }

    // ---- Phase B: stencil ----
    const float inv = gamma[c] * rsqrtf(var[c] + 1e-5f);
    const float bias = beta[c] - mean[c] * inv;

    const int ib = il * 16;                // strip base row
    const int t0 = ib - 6;

    float Wa[33], Wb[33];
    float racc[13];

    // Pass H: h1 + h2 -> att
#pragma unroll
    for (int k = 0; k < 33; ++k) {
        Wa[k] = wh1g[c * 33 + k];
        Wb[k] = wh2g[c * 33 + k];
    }
#pragma unroll
    for (int k = 0; k < 13; ++k) racc[k] = 0.f;
#pragma unroll
    for (int tt = 0; tt < 28; ++tt) {
        const int t = t0 + tt;
        if (t >= 0 && t < 64) {            // wave-uniform
            float w_[13];
#pragma unroll
            for (int d = 0; d < 13; ++d) w_[d] = T[t * 80 + j + d];
#pragma unroll
            for (int p = 0; p < 11; ++p) {
                racc[(tt + 11 - p) % 13] +=
                    Wa[p * 3 + 0] * w_[5] + Wa[p * 3 + 1] * w_[6] +
                    Wa[p * 3 + 2] * w_[7] +
                    Wb[p * 3 + 0] * w_[10 - p] +
                    Wb[p * 3 + 1] * w_[11 - p] +
                    Wb[p * 3 + 2] * w_[12 - p];
            }
        }
        if (tt >= 12) {                    // i = ib + tt - 12
            const int i = t - 6;
            att[i * 64 + j] = racc[tt % 13];
        }
        racc[tt % 13] = 0.f;
    }

    // Pass V: w1 + w2, BN + sigmoid -> gate in att[]
#pragma unroll
    for (int k = 0; k < 33; ++k) {
        Wa[k] = wv1g[c * 33 + k];
        Wb[k] = wv2g[c * 33 + k];
    }
#pragma unroll
    for (int k = 0; k < 13; ++k) racc[k] = 0.f;
#pragma unroll
    for (int tt = 0; tt < 28; ++tt) {
        const int t = t0 + tt;
        if (t >= 0 && t < 64) {            // wave-uniform
            float w_[13];
#pragma unroll
            for (int d = 0; d < 13; ++d) w_[d] = T[t * 80 + j + d];
#pragma unroll
            for (int p = 0; p < 3; ++p) {
#pragma unroll
                for (int q = 0; q < 11; ++q) {
                    racc[(tt + 7 - p) % 13] += Wa[p * 11 + q] * w_[q + 1];
                    racc[(tt + 2 - p + q) % 13] += Wb[p * 11 + q] * w_[q + 1];
                }
            }
        }
        if (tt >= 12) {
            const int i = t - 6;
            float z = (att[i * 64 + j] + racc[tt % 13]) * inv + bias;
            att[i * 64 + j] = 1.f / (1.f + __expf(-z));   // gate, in place
        }
        racc[tt % 13] = 0.f;
    }
    __syncthreads();

    // ---- Phase C: out = x * gate[i/3, j/3] ----
    const float4* xp4 = (const float4*)(x + (size_t)plane * 36864);
    float4* op4 = (float4*)(out + (size_t)plane * 36864);
#pragma unroll
    for (int bse = 0; bse < 9216; bse += 1024) {
        float4 xv[4];
        int e[4];
#pragma unroll
        for (int u = 0; u < 4; ++u) {
            e[u] = bse + u * 256 + threadIdx.x;
            xv[u] = xp4[e[u]];
        }
#pragma unroll
        for (int u = 0; u < 4; ++u) {
            int i = e[u] / 48, c4 = e[u] - i * 48;
            const float* gp = att + (i / 3) * 64;
            int jj = 4 * c4;
            int g0 = jj / 3;
            int r = jj - 3 * g0;
            float ga = gp[g0], gb = gp[g0 + 1];
            float4 o;
            o.x = xv[u].x * ga;
            o.y = xv[u].y * (r == 2 ? gb : ga);
            o.z = xv[u].z * (r == 0 ? ga : gb);
            o.w = xv[u].w * gb;
            op4[e[u]] = o;
        }
    }
}

extern "C" void kernel_launch(void* const* d_in, const int* in_sizes, int n_in,
                              void* d_out, int out_size, void* d_ws, size_t ws_size,
                              hipStream_t stream) {
    const float* x     = (const float*)d_in[0];
    const float* wh1   = (const float*)d_in[1];
    const float* wv1   = (const float*)d_in[2];
    const float* wh2   = (const float*)d_in[3];
    const float* wv2   = (const float*)d_in[4];
    const float* gamma = (const float*)d_in[5];
    const float* beta  = (const float*)d_in[6];
    const float* mean  = (const float*)d_in[7];
    const float* var   = (const float*)d_in[8];
    float* out  = (float*)d_out;

    mra_fused<<<1024, 256, 0, stream>>>(x, wh1, wv1, wh2, wv2,
                                        gamma, beta, mean, var, out);
}

// Round 4
// 304.630 us; speedup vs baseline: 1.2724x; 1.0240x over previous
//
#include <hip/hip_runtime.h>
#include <math.h>

// ---------------------------------------------------------------------------
// Fully fused MRA, de-serialized: one block = one plane (1024 blocks, 256 thr,
// 4 waves). ONE barrier in the whole kernel.
//
// Phase A (per-wave, barrier-free): maxpool3x3(s1,p1) + blurpool([1,3,3,1]^2
//   /64, s3, reflect(1,2)). Wave w computes T rows 16w..16w+15 directly from
//   global x with a rolling 6-row x 6-col register window (rows advance by 3
//   per output; 18 new scalar loads per output, wave-uniform row base).
//   Row/col clamp == replicate, valid for the max windows; blur reflect at
//   i=0 / j=0 handled by 1-op selects. T border cols stay zero (stencil pad).
// [barrier]
// Phase B pass H: h1+h2 partials -> wave-local rows of gateL (no barrier:
//   each wave reads/writes only its strip's gateL rows).
//   Rolling 13-deep accumulator as a ROTATING register file (full unroll:
//   tap for output i at phys (tt + i-(t-6)) % 13, emit from tt%13, zero it).
// Phase B pass V + Phase C interleaved: per tt>=12, finish gate row
//   i = ib+tt-12 (BN+sigmoid, in gateL, wave-coherent), then immediately
//   stream output rows 3i..3i+2 (144 float4 over 64 lanes: slots j, j+64,
//   j+128<144). x loads are L3-hot (phase A read the plane minutes of cycles
//   earlier); stores spread across the whole pass -> flat HBM demand.
//
// LDS = T(64x80=20480B) + gateL(64x64=16384B) = 36864 B; grid-limited at
// 4 blocks/CU. __launch_bounds__(256,4) pins VGPR<=128.
// ---------------------------------------------------------------------------
__global__ __launch_bounds__(256, 4) void mra_fused(
    const float* __restrict__ x,
    const float* __restrict__ wh1g, const float* __restrict__ wv1g,
    const float* __restrict__ wh2g, const float* __restrict__ wv2g,
    const float* __restrict__ gamma, const float* __restrict__ beta,
    const float* __restrict__ mean, const float* __restrict__ var,
    float* __restrict__ out) {
    const int plane = blockIdx.x;          // 0..1023
    const int c = plane & 63;
    __shared__ float T[64 * 80];           // pooled tile, cols 6..69 live
    __shared__ float gateL[64 * 64];       // H-partials -> gate (wave-local rows)

    const int j = threadIdx.x & 63;        // lane = column
    const int il = threadIdx.x >> 6;       // wave id 0..3
    const int ib = il * 16;                // strip base row

    // zero own strip of T (wave-local; no barrier needed before own writes)
    {
        float4 z4 = make_float4(0.f, 0.f, 0.f, 0.f);
        float4* t4 = (float4*)(T + ib * 80);   // 16*80 floats = 320 float4
#pragma unroll
        for (int u = 0; u < 5; ++u) t4[u * 64 + j] = z4;
    }

    const float* xp = x + (size_t)plane * 36864;

    // ---- Phase A: per-wave pooling into own strip of T ----
    {
        int colk[6];
#pragma unroll
        for (int k = 0; k < 6; ++k)
            colk[k] = min(max(3 * j - 2 + k, 0), 191);

        float rw[6][6];
#pragma unroll
        for (int s = 0; s < 6; ++s) {
            const float* rp = xp + (size_t)min(max(3 * ib - 2 + s, 0), 191) * 192;
#pragma unroll
            for (int k = 0; k < 6; ++k) rw[s][k] = rp[colk[k]];
        }

#define POOL_EMIT(I, S0, S1, S2, S3, S4, S5)                              \
        {                                                                 \
            float cbv[4];                                                 \
            {                                                             \
                float vmu[4][6];                                          \
                _Pragma("unroll") for (int k = 0; k < 6; ++k) {           \
                    float p0 = rw[S0][k], p1 = rw[S1][k], p2 = rw[S2][k]; \
                    float p3 = rw[S3][k], p4 = rw[S4][k], p5 = rw[S5][k]; \
                    float q1 = fmaxf(p1, p2), q2 = fmaxf(p2, p3);         \
                    float q3 = fmaxf(p3, p4), q4 = fmaxf(p4, p5);         \
                    vmu[0][k] = fmaxf(p0, q1);                            \
                    vmu[1][k] = fmaxf(p1, q2);                            \
                    vmu[2][k] = fmaxf(p2, q3);                            \
                    vmu[3][k] = fmaxf(p3, q4);                            \
                }                                                         \
                _Pragma("unroll") for (int u = 0; u < 4; ++u) {           \
                    float g1 = fmaxf(vmu[u][1], vmu[u][2]);               \
                    float g2 = fmaxf(vmu[u][2], vmu[u][3]);               \
                    float g3 = fmaxf(vmu[u][3], vmu[u][4]);               \
                    float g4 = fmaxf(vmu[u][4], vmu[u][5]);               \
                    float h0 = fmaxf(vmu[u][0], g1);                      \
                    float h1 = fmaxf(vmu[u][1], g2);                      \
                    float h2 = fmaxf(vmu[u][2], g3);                      \
                    float h3 = fmaxf(vmu[u][3], g4);                      \
                    float ha = (j == 0) ? h2 : h0;   /* col reflect */    \
                    cbv[u] = ha + 3.f * h1 + 3.f * h2 + h3;               \
                }                                                         \
            }                                                             \
            float c0 = ((I) == 0) ? cbv[2] : cbv[0]; /* row reflect */    \
            float accv = c0 + 3.f * cbv[1] + 3.f * cbv[2] + cbv[3];       \
            T[(I) * 80 + 6 + j] = accv * (1.f / 64.f);                    \
        }

#define LOAD3(BR, S0, S1, S2)                                             \
        {                                                                 \
            const float* rp0 = xp + (size_t)min((BR), 191) * 192;         \
            const float* rp1 = xp + (size_t)min((BR) + 1, 191) * 192;     \
            const float* rp2 = xp + (size_t)min((BR) + 2, 191) * 192;     \
            _Pragma("unroll") for (int k = 0; k < 6; ++k) {               \
                rw[S0][k] = rp0[colk[k]];                                 \
                rw[S1][k] = rp1[colk[k]];                                 \
                rw[S2][k] = rp2[colk[k]];                                 \
            }                                                             \
        }

#pragma unroll 1
        for (int ii = 0; ii < 16; ii += 2) {
            const int i = ib + ii;
            // slots 0..5 hold input rows 3i-2 .. 3i+3
            POOL_EMIT(i, 0, 1, 2, 3, 4, 5);
            LOAD3(3 * i + 4, 0, 1, 2);         // rows for output i+1
            POOL_EMIT(i + 1, 3, 4, 5, 0, 1, 2);
            if (ii < 14) LOAD3(3 * i + 7, 3, 4, 5);  // restore invariant
        }
#undef POOL_EMIT
#undef LOAD3
    }
    __syncthreads();   // the ONLY barrier: T complete incl. halo strips

    // ---- Phase B ----
    const float inv = gamma[c] * rsqrtf(var[c] + 1e-5f);
    const float bias = beta[c] - mean[c] * inv;
    const int t0 = ib - 6;

    float Wa[33], Wb[33];
    float racc[13];

    // Pass H: h1 + h2 -> gateL (wave-local rows)
#pragma unroll
    for (int k = 0; k < 33; ++k) {
        Wa[k] = wh1g[c * 33 + k];
        Wb[k] = wh2g[c * 33 + k];
    }
#pragma unroll
    for (int k = 0; k < 13; ++k) racc[k] = 0.f;
#pragma unroll
    for (int tt = 0; tt < 28; ++tt) {
        const int t = t0 + tt;
        if (t >= 0 && t < 64) {            // wave-uniform
            float w_[13];
#pragma unroll
            for (int d = 0; d < 13; ++d) w_[d] = T[t * 80 + j + d];
#pragma unroll
            for (int p = 0; p < 11; ++p) {
                racc[(tt + 11 - p) % 13] +=
                    Wa[p * 3 + 0] * w_[5] + Wa[p * 3 + 1] * w_[6] +
                    Wa[p * 3 + 2] * w_[7] +
                    Wb[p * 3 + 0] * w_[10 - p] +
                    Wb[p * 3 + 1] * w_[11 - p] +
                    Wb[p * 3 + 2] * w_[12 - p];
            }
        }
        if (tt >= 12) gateL[(ib + tt - 12) * 64 + j] = racc[tt % 13];
        racc[tt % 13] = 0.f;
    }

    // Phase C lane constants: float4 slots m = j, j+64, j+128 (<144)
    int g0s[3], rs[3];
#pragma unroll
    for (int u = 0; u < 3; ++u) {
        int m = j + 64 * u;
        int c4 = m % 48;
        int jj = 4 * c4;
        g0s[u] = jj / 3;
        rs[u] = jj - 3 * (jj / 3);
    }

    // Pass V (w1 + w2) + BN/sigmoid + streamed output (3 rows per gate row)
#pragma unroll
    for (int k = 0; k < 33; ++k) {
        Wa[k] = wv1g[c * 33 + k];
        Wb[k] = wv2g[c * 33 + k];
    }
#pragma unroll
    for (int k = 0; k < 13; ++k) racc[k] = 0.f;
    const float4* xp4 = (const float4*)xp;
    float4* op4 = (float4*)(out + (size_t)plane * 36864);
#pragma unroll
    for (int tt = 0; tt < 28; ++tt) {
        const int t = t0 + tt;
        if (t >= 0 && t < 64) {            // wave-uniform
            float w_[13];
#pragma unroll
            for (int d = 0; d < 13; ++d) w_[d] = T[t * 80 + j + d];
#pragma unroll
            for (int p = 0; p < 3; ++p) {
#pragma unroll
                for (int q = 0; q < 11; ++q) {
                    racc[(tt + 7 - p) % 13] += Wa[p * 11 + q] * w_[q + 1];
                    racc[(tt + 2 - p + q) % 13] += Wb[p * 11 + q] * w_[q + 1];
                }
            }
        }
        if (tt >= 12) {
            const int i = ib + tt - 12;
            const int fb = i * 144;        // float4 base of out rows 3i..3i+2
            // issue x loads early (independent of gate; L3-hot)
            float4 xv0 = xp4[fb + j];
            float4 xv1 = xp4[fb + 64 + j];
            float4 xv2;
            if (j < 16) xv2 = xp4[fb + 128 + j];
            // finish gate row i
            float z = (gateL[i * 64 + j] + racc[tt % 13]) * inv + bias;
            float g = 1.f / (1.f + __expf(-z));
            gateL[i * 64 + j] = g;         // wave-coherent (own row)
            const float* gr = gateL + i * 64;
            {
                float ga = gr[g0s[0]], gb = gr[g0s[0] + 1];
                float4 o;
                o.x = xv0.x * ga;
                o.y = xv0.y * (rs[0] == 2 ? gb : ga);
                o.z = xv0.z * (rs[0] == 0 ? ga : gb);
                o.w = xv0.w * gb;
                op4[fb + j] = o;
            }
            {
                float ga = gr[g0s[1]], gb = gr[g0s[1] + 1];
                float4 o;
                o.x = xv1.x * ga;
                o.y = xv1.y * (rs[1] == 2 ? gb : ga);
                o.z = xv1.z * (rs[1] == 0 ? ga : gb);
                o.w = xv1.w * gb;
                op4[fb + 64 + j] = o;
            }
            if (j < 16) {
                float ga = gr[g0s[2]], gb = gr[g0s[2] + 1];
                float4 o;
                o.x = xv2.x * ga;
                o.y = xv2.y * (rs[2] == 2 ? gb : ga);
                o.z = xv2.z * (rs[2] == 0 ? ga : gb);
                o.w = xv2.w * gb;
                op4[fb + 128 + j] = o;
            }
        }
        racc[tt % 13] = 0.f;
    }
}

extern "C" void kernel_launch(void* const* d_in, const int* in_sizes, int n_in,
                              void* d_out, int out_size, void* d_ws, size_t ws_size,
                              hipStream_t stream) {
    const float* x     = (const float*)d_in[0];
    const float* wh1   = (const float*)d_in[1];
    const float* wv1   = (const float*)d_in[2];
    const float* wh2   = (const float*)d_in[3];
    const float* wv2   = (const float*)d_in[4];
    const float* gamma = (const float*)d_in[5];
    const float* beta  = (const float*)d_in[6];
    const float* mean  = (const float*)d_in[7];
    const float* var   = (const float*)d_in[8];
    float* out  = (float*)d_out;

    mra_fused<<<1024, 256, 0, stream>>>(x, wh1, wv1, wh2, wv2,
                                        gamma, beta, mean, var, out);
}

// Round 5
// 297.019 us; speedup vs baseline: 1.3050x; 1.0256x over previous
//
#include <hip/hip_runtime.h>
#include <math.h>

// ---------------------------------------------------------------------------
// Fully fused MRA, occupancy-doubled: one block = one plane, 512 threads =
// 8 waves, each wave owns an 8-row strip of the 64x64 pooled tile. ONE
// barrier. LDS = T(64x80) + gateL(64x64) = 36864 B -> 4 blocks/CU; with
// VGPR <= 64 (launch_bounds(512,8); weights live in SGPRs - block-uniform)
// this reaches 32 waves/CU (100%) vs 16 before.
//
// Phase A (per-wave, barrier-free): maxpool3x3(s1,p1) + blurpool([1,3,3,1]^2
//   /64, s3, reflect(1,2)) directly from global x with a rolling 6x6 register
//   window (wave-uniform row base; row/col clamp == replicate is exact for
//   the max windows; blur reflect at i=0/j=0 via 1-op selects). Writes cols
//   6..69 of own T strip; border cols stay zero = stencil zero-pad.
// [barrier]
// Phase B pass H (h1+h2 -> gateL, wave-local rows), pass V (w1+w2) fused
//   with BN+sigmoid and Phase C streaming (out rows 3i..3i+2 per gate row).
//   Rolling 13-deep accumulator as a ROTATING register file (full unroll:
//   tap for output i at phys (tt + i-(t-6)) % 13; emit from tt%13; zero it).
//   Strip loops are 20 iterations (8 emits) instead of 28/16 - the extra
//   fill VALU is the price for 2x wave-level latency hiding.
// ---------------------------------------------------------------------------
__global__ __launch_bounds__(512, 8) void mra_fused(
    const float* __restrict__ x,
    const float* __restrict__ wh1g, const float* __restrict__ wv1g,
    const float* __restrict__ wh2g, const float* __restrict__ wv2g,
    const float* __restrict__ gamma, const float* __restrict__ beta,
    const float* __restrict__ mean, const float* __restrict__ var,
    float* __restrict__ out) {
    const int plane = blockIdx.x;          // 0..1023
    const int c = plane & 63;
    __shared__ float T[64 * 80];           // pooled tile, cols 6..69 live
    __shared__ float gateL[64 * 64];       // H-partials -> gate (wave-local rows)

    const int j = threadIdx.x & 63;        // lane = column
    const int il = threadIdx.x >> 6;       // wave id 0..7
    const int ib = il * 8;                 // strip base row

    // zero own 8-row strip of T (wave-local)
    {
        float4 z4 = make_float4(0.f, 0.f, 0.f, 0.f);
        float4* t4 = (float4*)(T + ib * 80);   // 8*80 floats = 160 float4
#pragma unroll
        for (int u = 0; u < 3; ++u) {
            int idx = u * 64 + j;
            if (idx < 160) t4[idx] = z4;
        }
    }

    const float* xp = x + (size_t)plane * 36864;

    // ---- Phase A: per-wave pooling into own strip of T ----
    {
        int colk[6];
#pragma unroll
        for (int k = 0; k < 6; ++k)
            colk[k] = min(max(3 * j - 2 + k, 0), 191);

        float rw[6][6];
#pragma unroll
        for (int s = 0; s < 6; ++s) {
            const float* rp = xp + (size_t)min(max(3 * ib - 2 + s, 0), 191) * 192;
#pragma unroll
            for (int k = 0; k < 6; ++k) rw[s][k] = rp[colk[k]];
        }

#define POOL_EMIT(I, S0, S1, S2, S3, S4, S5)                              \
        {                                                                 \
            float cbv[4];                                                 \
            {                                                             \
                float vmu[4][6];                                          \
                _Pragma("unroll") for (int k = 0; k < 6; ++k) {           \
                    float p0 = rw[S0][k], p1 = rw[S1][k], p2 = rw[S2][k]; \
                    float p3 = rw[S3][k], p4 = rw[S4][k], p5 = rw[S5][k]; \
                    float q1 = fmaxf(p1, p2), q2 = fmaxf(p2, p3);         \
                    float q3 = fmaxf(p3, p4), q4 = fmaxf(p4, p5);         \
                    vmu[0][k] = fmaxf(p0, q1);                            \
                    vmu[1][k] = fmaxf(p1, q2);                            \
                    vmu[2][k] = fmaxf(p2, q3);                            \
                    vmu[3][k] = fmaxf(p3, q4);                            \
                }                                                         \
                _Pragma("unroll") for (int u = 0; u < 4; ++u) {           \
                    float g1 = fmaxf(vmu[u][1], vmu[u][2]);               \
                    float g2 = fmaxf(vmu[u][2], vmu[u][3]);               \
                    float g3 = fmaxf(vmu[u][3], vmu[u][4]);               \
                    float g4 = fmaxf(vmu[u][4], vmu[u][5]);               \
                    float h0 = fmaxf(vmu[u][0], g1);                      \
                    float h1 = fmaxf(vmu[u][1], g2);                      \
                    float h2 = fmaxf(vmu[u][2], g3);                      \
                    float h3 = fmaxf(vmu[u][3], g4);                      \
                    float ha = (j == 0) ? h2 : h0;   /* col reflect */    \
                    cbv[u] = ha + 3.f * h1 + 3.f * h2 + h3;               \
                }                                                         \
            }                                                             \
            float c0 = ((I) == 0) ? cbv[2] : cbv[0]; /* row reflect */    \
            float accv = c0 + 3.f * cbv[1] + 3.f * cbv[2] + cbv[3];       \
            T[(I) * 80 + 6 + j] = accv * (1.f / 64.f);                    \
        }

#define LOAD3(BR, S0, S1, S2)                                             \
        {                                                                 \
            const float* rp0 = xp + (size_t)min((BR), 191) * 192;         \
            const float* rp1 = xp + (size_t)min((BR) + 1, 191) * 192;     \
            const float* rp2 = xp + (size_t)min((BR) + 2, 191) * 192;     \
            _Pragma("unroll") for (int k = 0; k < 6; ++k) {               \
                rw[S0][k] = rp0[colk[k]];                                 \
                rw[S1][k] = rp1[colk[k]];                                 \
                rw[S2][k] = rp2[colk[k]];                                 \
            }                                                             \
        }

#pragma unroll 1
        for (int ii = 0; ii < 8; ii += 2) {
            const int i = ib + ii;
            // slots 0..5 hold input rows 3i-2 .. 3i+3
            POOL_EMIT(i, 0, 1, 2, 3, 4, 5);
            LOAD3(3 * i + 4, 0, 1, 2);         // rows for output i+1
            POOL_EMIT(i + 1, 3, 4, 5, 0, 1, 2);
            if (ii < 6) LOAD3(3 * i + 7, 3, 4, 5);  // restore invariant
        }
#undef POOL_EMIT
#undef LOAD3
    }
    __syncthreads();   // the ONLY barrier: T complete incl. halo strips

    // ---- Phase B ----
    const float inv = gamma[c] * rsqrtf(var[c] + 1e-5f);
    const float bias = beta[c] - mean[c] * inv;
    const int t0 = ib - 6;

    float Wa[33], Wb[33];
    float racc[13];

    // Pass H: h1 + h2 -> gateL (wave-local rows)
#pragma unroll
    for (int k = 0; k < 33; ++k) {
        Wa[k] = wh1g[c * 33 + k];
        Wb[k] = wh2g[c * 33 + k];
    }
#pragma unroll
    for (int k = 0; k < 13; ++k) racc[k] = 0.f;
#pragma unroll
    for (int tt = 0; tt < 20; ++tt) {
        const int t = t0 + tt;
        if (t >= 0 && t < 64) {            // wave-uniform
            float w_[13];
#pragma unroll
            for (int d = 0; d < 13; ++d) w_[d] = T[t * 80 + j + d];
#pragma unroll
            for (int p = 0; p < 11; ++p) {
                racc[(tt + 11 - p) % 13] +=
                    Wa[p * 3 + 0] * w_[5] + Wa[p * 3 + 1] * w_[6] +
                    Wa[p * 3 + 2] * w_[7] +
                    Wb[p * 3 + 0] * w_[10 - p] +
                    Wb[p * 3 + 1] * w_[11 - p] +
                    Wb[p * 3 + 2] * w_[12 - p];
            }
        }
        if (tt >= 12) gateL[(ib + tt - 12) * 64 + j] = racc[tt % 13];
        racc[tt % 13] = 0.f;
    }

    // Phase C lane constants: float4 slots m = j, j+64, j+128 (<144)
    int g0s[3], rs[3];
#pragma unroll
    for (int u = 0; u < 3; ++u) {
        int m = j + 64 * u;
        int c4 = m % 48;
        int jj = 4 * c4;
        g0s[u] = jj / 3;
        rs[u] = jj - 3 * (jj / 3);
    }

    // Pass V (w1 + w2) + BN/sigmoid + streamed output (3 rows per gate row)
#pragma unroll
    for (int k = 0; k < 33; ++k) {
        Wa[k] = wv1g[c * 33 + k];
        Wb[k] = wv2g[c * 33 + k];
    }
#pragma unroll
    for (int k = 0; k < 13; ++k) racc[k] = 0.f;
    const float4* xp4 = (const float4*)xp;
    float4* op4 = (float4*)(out + (size_t)plane * 36864);
#pragma unroll
    for (int tt = 0; tt < 20; ++tt) {
        const int t = t0 + tt;
        if (t >= 0 && t < 64) {            // wave-uniform
            float w_[13];
#pragma unroll
            for (int d = 0; d < 13; ++d) w_[d] = T[t * 80 + j + d];
#pragma unroll
            for (int p = 0; p < 3; ++p) {
#pragma unroll
                for (int q = 0; q < 11; ++q) {
                    racc[(tt + 7 - p) % 13] += Wa[p * 11 + q] * w_[q + 1];
                    racc[(tt + 2 - p + q) % 13] += Wb[p * 11 + q] * w_[q + 1];
                }
            }
        }
        if (tt >= 12) {
            const int i = ib + tt - 12;
            const int fb = i * 144;        // float4 base of out rows 3i..3i+2
            // issue x loads early (independent of gate; L3-hot)
            float4 xv0 = xp4[fb + j];
            float4 xv1 = xp4[fb + 64 + j];
            float4 xv2;
            if (j < 16) xv2 = xp4[fb + 128 + j];
            // finish gate row i
            float z = (gateL[i * 64 + j] + racc[tt % 13]) * inv + bias;
            float g = 1.f / (1.f + __expf(-z));
            gateL[i * 64 + j] = g;         // wave-coherent (own row)
            const float* gr = gateL + i * 64;
            {
                float ga = gr[g0s[0]], gb = gr[g0s[0] + 1];
                float4 o;
                o.x = xv0.x * ga;
                o.y = xv0.y * (rs[0] == 2 ? gb : ga);
                o.z = xv0.z * (rs[0] == 0 ? ga : gb);
                o.w = xv0.w * gb;
                op4[fb + j] = o;
            }
            {
                float ga = gr[g0s[1]], gb = gr[g0s[1] + 1];
                float4 o;
                o.x = xv1.x * ga;
                o.y = xv1.y * (rs[1] == 2 ? gb : ga);
                o.z = xv1.z * (rs[1] == 0 ? ga : gb);
                o.w = xv1.w * gb;
                op4[fb + 64 + j] = o;
            }
            if (j < 16) {
                float ga = gr[g0s[2]], gb = gr[g0s[2] + 1];
                float4 o;
                o.x = xv2.x * ga;
                o.y = xv2.y * (rs[2] == 2 ? gb : ga);
                o.z = xv2.z * (rs[2] == 0 ? ga : gb);
                o.w = xv2.w * gb;
                op4[fb + 128 + j] = o;
            }
        }
        racc[tt % 13] = 0.f;
    }
}

extern "C" void kernel_launch(void* const* d_in, const int* in_sizes, int n_in,
                              void* d_out, int out_size, void* d_ws, size_t ws_size,
                              hipStream_t stream) {
    const float* x     = (const float*)d_in[0];
    const float* wh1   = (const float*)d_in[1];
    const float* wv1   = (const float*)d_in[2];
    const float* wh2   = (const float*)d_in[3];
    const float* wv2   = (const float*)d_in[4];
    const float* gamma = (const float*)d_in[5];
    const float* beta  = (const float*)d_in[6];
    const float* mean  = (const float*)d_in[7];
    const float* var   = (const float*)d_in[8];
    float* out  = (float*)d_out;

    mra_fused<<<1024, 512, 0, stream>>>(x, wh1, wv1, wh2, wv2,
                                        gamma, beta, mean, var, out);
}